// Round 6
// baseline (289.517 us; speedup 1.0000x reference)
//
#include <hip/hip_runtime.h>
#include <math.h>

#define Bdim 2
#define Sdim 2048
#define Ddim 1024
#define Hnum 16
#define HDdim 64
#define Kdim 1024

using short8   = __attribute__((ext_vector_type(8))) short;
using ushort8  = __attribute__((ext_vector_type(8))) unsigned short;
using ushort4v = __attribute__((ext_vector_type(4))) unsigned short;
using floatx4  = __attribute__((ext_vector_type(4))) float;
using half4    = __attribute__((ext_vector_type(4))) _Float16;

__device__ __forceinline__ unsigned short f2bf(float f) {
    __bf16 b = (__bf16)f;
    return __builtin_bit_cast(unsigned short, b);
}

// async global->LDS, 16B per lane. LDS dest is wave-uniform base + lane*16.
__device__ __forceinline__ void async_ld16(const unsigned short* g, unsigned short* l) {
    __builtin_amdgcn_global_load_lds(
        (const __attribute__((address_space(1))) unsigned int*)(g),
        (__attribute__((address_space(3))) unsigned int*)(l), 16, 0, 0);
}

// ---------------------------------------------------------------------------
// x fp32 -> bf16 (same layout).
// ---------------------------------------------------------------------------
__global__ __launch_bounds__(256) void convert_x_kernel(
    const float* __restrict__ x, unsigned short* __restrict__ xb)
{
    size_t i = ((size_t)blockIdx.x * 256 + threadIdx.x) * 8;
    float4 a = *(const float4*)(x + i);
    float4 b = *(const float4*)(x + i + 4);
    ushort8 o;
    o[0] = f2bf(a.x); o[1] = f2bf(a.y); o[2] = f2bf(a.z); o[3] = f2bf(a.w);
    o[4] = f2bf(b.x); o[5] = f2bf(b.y); o[6] = f2bf(b.z); o[7] = f2bf(b.w);
    *(ushort8*)(xb + i) = o;
}

// ---------------------------------------------------------------------------
// W [k][n] fp32 -> Wt [mat][n][k] bf16 (transpose), 64x64 tiles via LDS.
// ---------------------------------------------------------------------------
__global__ __launch_bounds__(256) void transpose_w_kernel(
    const float* __restrict__ Wq, const float* __restrict__ Wk,
    const float* __restrict__ Wv, const float* __restrict__ Wo,
    unsigned short* __restrict__ Wt)
{
    __shared__ float tile[64][65];
    const int z = blockIdx.z;
    const float* W = (z == 0) ? Wq : (z == 1) ? Wk : (z == 2) ? Wv : Wo;
    unsigned short* outp = Wt + (size_t)z * Kdim * Ddim;
    const int n0 = blockIdx.x * 64;
    const int k0 = blockIdx.y * 64;
    const int t = threadIdx.x;
#pragma unroll
    for (int i = 0; i < 4; ++i) {
        int flat = i * 256 + t;
        int r = flat >> 4;
        int c = (flat & 15) * 4;
        float4 v = *(const float4*)(W + (size_t)(k0 + r) * Ddim + n0 + c);
        tile[r][c] = v.x; tile[r][c + 1] = v.y; tile[r][c + 2] = v.z; tile[r][c + 3] = v.w;
    }
    __syncthreads();
#pragma unroll
    for (int i = 0; i < 16; ++i) {
        int flat = i * 256 + t;
        int n = flat >> 6;
        int k = flat & 63;
        outp[(size_t)(n0 + n) * Kdim + k0 + k] = f2bf(tile[k][n]);
    }
}

// ---------------------------------------------------------------------------
// Pack mask into per-wave lane-mask words:
// word[b][qg][kb16][r], bit(lane) = mask[b][qg*16+(lane&15)][kb16*16+(lane>>4)*4+r]
// ---------------------------------------------------------------------------
__global__ __launch_bounds__(256) void pack_mask_kernel(
    const int* __restrict__ mask, unsigned long long* __restrict__ packed)
{
    const int t    = threadIdx.x;
    const int lane = t & 63;
    const int l15  = lane & 15;
    const int quad = lane >> 4;
    const unsigned int widx = blockIdx.x * 4 + (t >> 6);
    const int r  = widx & 3;
    const int kb = (widx >> 2) & 127;
    const int qg = (widx >> 9) & 127;
    const int b  = widx >> 16;
    int mv = mask[((size_t)(b * Sdim) + qg * 16 + l15) * Sdim + kb * 16 + quad * 4 + r];
    unsigned long long bits = __ballot(mv != 0);
    if (lane == 0) packed[widx] = bits;
}

// ---------------------------------------------------------------------------
// bf16 MFMA GEMM cores (m97 structure), 128x128 tile, BK=64, 2x2 waves x 4x4.
// GEMM_CORE:   acc = A-tile . W-tile^T      (C:  lane col=l15=n, rows=quad*4+r=m)
// GEMM_CORE_T: acc = (A-tile . W-tile^T)^T  (C': lane col=l15=m(s), rows=4 contig n)
//   -- operand-swapped mfma; A/B frags have identical layouts so this is free.
// ---------------------------------------------------------------------------
#define GEMM_STAGE_AND_FRAGS(APTR, WPTR)                                         \
    __shared__ __align__(16) unsigned short As[128 * 64];                        \
    __shared__ __align__(16) unsigned short Bs[128 * 64];                        \
    const int t    = threadIdx.x;                                                \
    const int lane = t & 63;                                                     \
    const int w    = t >> 6;                                                     \
    const int quad = lane >> 4;                                                  \
    const int l15  = lane & 15;                                                  \
    const int wm   = w & 1;                                                      \
    const int wn   = w >> 1;                                                     \
    floatx4 acc[4][4];                                                           \
    _Pragma("unroll")                                                            \
    for (int mt = 0; mt < 4; ++mt)                                               \
        _Pragma("unroll")                                                        \
        for (int nt = 0; nt < 4; ++nt) acc[mt][nt] = (floatx4){0.f,0.f,0.f,0.f};

#define GEMM_KLOOP(APTR, WPTR, MFMA_STMT)                                        \
    for (int kt = 0; kt < 16; ++kt) {                                            \
        const int k0 = kt * 64;                                                  \
        __syncthreads();                                                         \
        _Pragma("unroll")                                                        \
        for (int i = 0; i < 4; ++i) {                                            \
            int flat = i * 256 + t;                                              \
            int row  = flat >> 3;                                                \
            int cg   = (flat & 7) ^ (row & 7);                                   \
            async_ld16(APTR + (size_t)(m0 + row) * Kdim + k0 + cg * 8,           \
                       As + flat * 8);                                           \
        }                                                                        \
        _Pragma("unroll")                                                        \
        for (int i = 0; i < 4; ++i) {                                            \
            int flat = i * 256 + t;                                              \
            int row  = flat >> 3;                                                \
            int cg   = (flat & 7) ^ (row & 7);                                   \
            async_ld16(WPTR + (size_t)row * Kdim + k0 + cg * 8,                  \
                       Bs + flat * 8);                                           \
        }                                                                        \
        __syncthreads();                                                         \
        _Pragma("unroll")                                                        \
        for (int ks = 0; ks < 2; ++ks) {                                         \
            short8 af[4], bfr[4];                                                \
            _Pragma("unroll")                                                    \
            for (int mt = 0; mt < 4; ++mt) {                                     \
                int row = wm * 64 + mt * 16 + l15;                               \
                int ch  = (ks * 4 + quad) ^ (row & 7);                           \
                af[mt] = *(const short8*)(As + row * 64 + ch * 8);               \
            }                                                                    \
            _Pragma("unroll")                                                    \
            for (int nt = 0; nt < 4; ++nt) {                                     \
                int row = wn * 64 + nt * 16 + l15;                               \
                int ch  = (ks * 4 + quad) ^ (row & 7);                           \
                bfr[nt] = *(const short8*)(Bs + row * 64 + ch * 8);              \
            }                                                                    \
            _Pragma("unroll")                                                    \
            for (int mt = 0; mt < 4; ++mt)                                       \
                _Pragma("unroll")                                                \
                for (int nt = 0; nt < 4; ++nt)                                   \
                    MFMA_STMT;                                                   \
        }                                                                        \
    }

#define MFMA_NORM acc[mt][nt] = __builtin_amdgcn_mfma_f32_16x16x32_bf16(af[mt], bfr[nt], acc[mt][nt], 0, 0, 0)
#define MFMA_SWAP acc[mt][nt] = __builtin_amdgcn_mfma_f32_16x16x32_bf16(bfr[nt], af[mt], acc[mt][nt], 0, 0, 0)

// ---------------------------------------------------------------------------
// Q/K projection (operand-swapped): writes bf16 [bh][s][hd] with ushort4 stores.
// grid (16, 32): n0 in [0,2048) covers q (wsel=0) then k (wsel=1).
// ---------------------------------------------------------------------------
__global__ __launch_bounds__(256) void qk_mfma_kernel(
    const unsigned short* __restrict__ A, const unsigned short* __restrict__ Wt,
    const float* __restrict__ bq, const float* __restrict__ bk,
    unsigned short* __restrict__ qo, unsigned short* __restrict__ ko)
{
    const int n0   = blockIdx.x * 128;
    const int m0   = blockIdx.y * 128;
    const int wsel = n0 >> 10;
    const int c0   = n0 & 1023;
    const unsigned short* Wp = Wt + (size_t)wsel * Kdim * Ddim + (size_t)c0 * Kdim;

    GEMM_STAGE_AND_FRAGS(A, Wp)
    GEMM_KLOOP(A, Wp, MFMA_SWAP)

    const float* bias = wsel ? bk : bq;
    unsigned short* outp = wsel ? ko : qo;
    const float qsc = wsel ? 1.0f : 0.18033688011112042f;  // q: 0.125*log2(e)
#pragma unroll
    for (int mt = 0; mt < 4; ++mt) {
        int m    = m0 + wm * 64 + mt * 16 + l15;  // s-row
        int bidx = m >> 11;
        int s    = m & 2047;
#pragma unroll
        for (int nt = 0; nt < 4; ++nt) {
            int c = c0 + wn * 64 + nt * 16 + quad * 4;  // 4 contiguous cols
            float4 bb = *(const float4*)(bias + c);
            int h  = c >> 6;
            int hd = c & 63;
            ushort4v o;
            o[0] = f2bf((acc[mt][nt][0] + bb.x) * qsc);
            o[1] = f2bf((acc[mt][nt][1] + bb.y) * qsc);
            o[2] = f2bf((acc[mt][nt][2] + bb.z) * qsc);
            o[3] = f2bf((acc[mt][nt][3] + bb.w) * qsc);
            *(ushort4v*)(outp + ((size_t)(bidx * Hnum + h) * Sdim + s) * HDdim + hd) = o;
        }
    }
}

// ---------------------------------------------------------------------------
// V projection (normal order): writes f16 TRANSPOSED [bh][hd][s], half4 stores.
// grid (8, 32).
// ---------------------------------------------------------------------------
__global__ __launch_bounds__(256) void v_mfma_kernel(
    const unsigned short* __restrict__ A, const unsigned short* __restrict__ Wt,
    const float* __restrict__ bv, _Float16* __restrict__ vto)
{
    const int n0 = blockIdx.x * 128;
    const int m0 = blockIdx.y * 128;
    const unsigned short* Wp = Wt + (size_t)2 * Kdim * Ddim + (size_t)n0 * Kdim;

    GEMM_STAGE_AND_FRAGS(A, Wp)
    GEMM_KLOOP(A, Wp, MFMA_NORM)

#pragma unroll
    for (int nt = 0; nt < 4; ++nt) {
        int c = n0 + wn * 64 + nt * 16 + l15;
        float bb = bv[c];
        int h  = c >> 6;
        int hd = c & 63;
#pragma unroll
        for (int mt = 0; mt < 4; ++mt) {
            int m    = m0 + wm * 64 + mt * 16 + quad * 4;  // 4 contiguous s
            int bidx = m >> 11;
            int s    = m & 2047;
            half4 o;
#pragma unroll
            for (int r = 0; r < 4; ++r) o[r] = (_Float16)(acc[mt][nt][r] + bb);
            *(half4*)(vto + ((size_t)(bidx * Hnum + h) * HDdim + hd) * Sdim + s) = o;
        }
    }
}

// ---------------------------------------------------------------------------
// Output projection (operand-swapped): fp32 out + bias, float4 coalesced stores.
// grid (8, 32).
// ---------------------------------------------------------------------------
__global__ __launch_bounds__(256) void out_mfma_kernel(
    const unsigned short* __restrict__ A, const unsigned short* __restrict__ Wt,
    const float* __restrict__ bias, float* __restrict__ out)
{
    const int n0 = blockIdx.x * 128;
    const int m0 = blockIdx.y * 128;
    const unsigned short* Wp = Wt + (size_t)3 * Kdim * Ddim + (size_t)n0 * Kdim;

    GEMM_STAGE_AND_FRAGS(A, Wp)
    GEMM_KLOOP(A, Wp, MFMA_SWAP)

#pragma unroll
    for (int mt = 0; mt < 4; ++mt) {
        int m = m0 + wm * 64 + mt * 16 + l15;  // s-row
#pragma unroll
        for (int nt = 0; nt < 4; ++nt) {
            int c = n0 + wn * 64 + nt * 16 + quad * 4;
            float4 bb = *(const float4*)(bias + c);
            float4 o = make_float4(acc[mt][nt][0] + bb.x, acc[mt][nt][1] + bb.y,
                                   acc[mt][nt][2] + bb.z, acc[mt][nt][3] + bb.w);
            *(float4*)(out + (size_t)m * Ddim + c) = o;
        }
    }
}

// ---------------------------------------------------------------------------
// MFMA flash attention v3 (unchanged from round 5): DMA-staged K/V (double-
// buffered LDS), transposed scores, P in registers, mask via SGPR v_cndmask,
// l via ones-MFMA. Block = 2 waves x 64 q-rows; grid 1024, bh = bid&31.
// ---------------------------------------------------------------------------
__global__ __launch_bounds__(128, 2) void attn_mfma_kernel(
    const unsigned short* __restrict__ q, const unsigned short* __restrict__ k,
    const _Float16* __restrict__ vt, const unsigned long long* __restrict__ pmask,
    unsigned short* __restrict__ ctx)
{
    __shared__ __align__(16) unsigned short Ks[2][64 * 64];  // [key][hd], swizzled
    __shared__ __align__(16) _Float16       Vs[2][64 * 64];  // [hd][key], swizzled

    const int t    = threadIdx.x;
    const int w    = t >> 6;
    const int lane = t & 63;
    const int quad = lane >> 4;
    const int l15  = lane & 15;
    const int bid  = blockIdx.x;
    const int bh   = bid & 31;
    const int qseg = bid >> 5;
    const int b    = bh >> 4;
    const int h    = bh & 15;
    const int qrow0 = qseg * 64 + w * 32;

    const unsigned short* qp = q  + (size_t)bh * Sdim * HDdim;
    const unsigned short* kp = k  + (size_t)bh * Sdim * HDdim;
    const _Float16*       vp = vt + (size_t)bh * HDdim * Sdim;

    const int qg0 = __builtin_amdgcn_readfirstlane(qrow0 >> 4);
    const unsigned long long* __restrict__ pm =
        pmask + ((size_t)(b * 128 + qg0) * 128) * 4;

    short8 qf[2][2];
#pragma unroll
    for (int g = 0; g < 2; ++g)
#pragma unroll
        for (int ks = 0; ks < 2; ++ks)
            qf[g][ks] = *(const short8*)(qp + (size_t)(qrow0 + g * 16 + l15) * HDdim + ks * 32 + quad * 8);

    floatx4 acc[2][4];
    floatx4 accl[2];
#pragma unroll
    for (int g = 0; g < 2; ++g) {
        accl[g] = (floatx4){0.f, 0.f, 0.f, 0.f};
#pragma unroll
        for (int hs = 0; hs < 4; ++hs) acc[g][hs] = (floatx4){0.f, 0.f, 0.f, 0.f};
    }
    const half4 ones = {(_Float16)1.f, (_Float16)1.f, (_Float16)1.f, (_Float16)1.f};

    auto stage = [&](int buf, int key0) {
#pragma unroll
        for (int i = 0; i < 4; ++i) {
            int flat = i * 128 + t;
            int row  = flat >> 3;
            int cg   = (flat & 7) ^ (row & 7);
            async_ld16(kp + (size_t)(key0 + row) * HDdim + cg * 8, &Ks[buf][flat * 8]);
        }
#pragma unroll
        for (int i = 0; i < 4; ++i) {
            int flat = i * 128 + t;
            int row  = flat >> 3;
            int cg   = (flat & 7) ^ (row & 7);
            async_ld16((const unsigned short*)(vp + (size_t)row * Sdim + key0 + cg * 8),
                       (unsigned short*)&Vs[buf][flat * 8]);
        }
    };

    stage(0, 0);

#pragma unroll 2
    for (int kt = 0; kt < 32; ++kt) {
        const int cur = kt & 1;
        __syncthreads();
        if (kt < 31) stage(cur ^ 1, (kt + 1) * 64);

        short8 kf[2][4];
#pragma unroll
        for (int ks = 0; ks < 2; ++ks)
#pragma unroll
            for (int sub = 0; sub < 4; ++sub) {
                int row = sub * 16 + l15;
                int ch  = (ks * 4 + quad) ^ (row & 7);
                kf[ks][sub] = *(const short8*)&Ks[cur][row * 64 + ch * 8];
            }
        half4 vf[4][4];
#pragma unroll
        for (int hs = 0; hs < 4; ++hs)
#pragma unroll
            for (int c = 0; c < 4; ++c) {
                int row = hs * 16 + l15;
                int cc  = c * 2 + (quad >> 1);
                int ch  = cc ^ (row & 7);
                vf[hs][c] = *(const half4*)&Vs[cur][row * 64 + ch * 8 + (quad & 1) * 4];
            }

        floatx4 sc[2][4];
#pragma unroll
        for (int g = 0; g < 2; ++g)
#pragma unroll
            for (int sub = 0; sub < 4; ++sub) sc[g][sub] = (floatx4){0.f, 0.f, 0.f, 0.f};
#pragma unroll
        for (int ks = 0; ks < 2; ++ks)
#pragma unroll
            for (int sub = 0; sub < 4; ++sub)
#pragma unroll
                for (int g = 0; g < 2; ++g)
                    sc[g][sub] = __builtin_amdgcn_mfma_f32_16x16x32_bf16(
                        kf[ks][sub], qf[g][ks], sc[g][sub], 0, 0, 0);

        half4 pf[2][4];
#pragma unroll
        for (int g = 0; g < 2; ++g) {
            const unsigned long long* __restrict__ pg = pm + g * 512 + kt * 16;
#pragma unroll
            for (int c = 0; c < 4; ++c) {
#pragma unroll
                for (int r = 0; r < 4; ++r) {
                    float p = exp2f(sc[g][c][r]);
                    unsigned long long wmask = pg[c * 4 + r];
                    float pmv;
                    asm("v_cndmask_b32 %0, 0, %1, %2" : "=v"(pmv) : "v"(p), "s"(wmask));
                    pf[g][c][r] = (_Float16)pmv;
                }
            }
        }

#pragma unroll
        for (int c = 0; c < 4; ++c) {
#pragma unroll
            for (int hs = 0; hs < 4; ++hs)
#pragma unroll
                for (int g = 0; g < 2; ++g)
                    acc[g][hs] = __builtin_amdgcn_mfma_f32_16x16x16f16(
                        vf[hs][c], pf[g][c], acc[g][hs], 0, 0, 0);
#pragma unroll
            for (int g = 0; g < 2; ++g)
                accl[g] = __builtin_amdgcn_mfma_f32_16x16x16f16(
                    ones, pf[g][c], accl[g], 0, 0, 0);
        }
    }

#pragma unroll
    for (int g = 0; g < 2; ++g) {
        float inv = 1.0f / fmaxf(accl[g][0], 1e-30f);
        int row = qrow0 + g * 16 + l15;
#pragma unroll
        for (int hs = 0; hs < 4; ++hs) {
            ushort4v o;
#pragma unroll
            for (int r = 0; r < 4; ++r) o[r] = f2bf(acc[g][hs][r] * inv);
            *(ushort4v*)(ctx + (size_t)(b * Sdim + row) * Ddim + h * 64 + hs * 16 + quad * 4) = o;
        }
    }
}

// ---------------------------------------------------------------------------
extern "C" void kernel_launch(void* const* d_in, const int* in_sizes, int n_in,
                              void* d_out, int out_size, void* d_ws, size_t ws_size,
                              hipStream_t stream) {
    const float* x   = (const float*)d_in[0];
    const float* Wq  = (const float*)d_in[1];
    const float* bq  = (const float*)d_in[2];
    const float* Wk  = (const float*)d_in[3];
    const float* bk  = (const float*)d_in[4];
    const float* Wv  = (const float*)d_in[5];
    const float* bv  = (const float*)d_in[6];
    const float* Wo  = (const float*)d_in[7];
    const float* bo  = (const float*)d_in[8];
    // d_in[9] cross_modal_weights: softmax-shift-invariant -> unused
    const int*  mask = (const int*)d_in[10];
    // d_in[11] modality_info: unused by the reference
    float* out = (float*)d_out;

    char* ws = (char*)d_ws;
    unsigned short* xb  = (unsigned short*)(ws);                         // 8 MB
    unsigned short* Wt  = (unsigned short*)(ws + (size_t)8  * 1048576);  // 8 MB
    unsigned short* qb  = (unsigned short*)(ws + (size_t)16 * 1048576);  // 8 MB
    unsigned short* kb  = (unsigned short*)(ws + (size_t)24 * 1048576);  // 8 MB
    _Float16*       vtb = (_Float16*)     (ws + (size_t)32 * 1048576);   // 8 MB f16 [bh][hd][s]
    unsigned long long* pmk = (unsigned long long*)(ws + (size_t)40 * 1048576); // 1 MB
    unsigned short* ctxb = xb;  // alias: xb consumed before attn writes ctx

    convert_x_kernel<<<dim3(2048), 256, 0, stream>>>(x, xb);
    transpose_w_kernel<<<dim3(16, 16, 4), 256, 0, stream>>>(Wq, Wk, Wv, Wo, Wt);
    pack_mask_kernel<<<dim3(32768), 256, 0, stream>>>(mask, pmk);
    qk_mfma_kernel<<<dim3(16, 32), 256, 0, stream>>>(xb, Wt, bq, bk, qb, kb);
    v_mfma_kernel<<<dim3(8, 32), 256, 0, stream>>>(xb, Wt, bv, vtb);
    attn_mfma_kernel<<<dim3(1024), 128, 0, stream>>>(qb, kb, vtb, pmk, ctxb);
    out_mfma_kernel<<<dim3(8, 32), 256, 0, stream>>>(ctxb, Wt, bo, out);
}

// Round 7
// 275.460 us; speedup vs baseline: 1.0510x; 1.0510x over previous
//
#include <hip/hip_runtime.h>
#include <math.h>

#define Bdim 2
#define Sdim 2048
#define Ddim 1024
#define Hnum 16
#define HDdim 64
#define Kdim 1024

using short8   = __attribute__((ext_vector_type(8))) short;
using ushort8  = __attribute__((ext_vector_type(8))) unsigned short;
using ushort4v = __attribute__((ext_vector_type(4))) unsigned short;
using floatx4  = __attribute__((ext_vector_type(4))) float;
using half4    = __attribute__((ext_vector_type(4))) _Float16;

__device__ __forceinline__ unsigned short f2bf(float f) {
    __bf16 b = (__bf16)f;
    return __builtin_bit_cast(unsigned short, b);
}

// async global->LDS, 16B per lane. LDS dest is wave-uniform base + lane*16.
__device__ __forceinline__ void async_ld16(const unsigned short* g, unsigned short* l) {
    __builtin_amdgcn_global_load_lds(
        (const __attribute__((address_space(1))) unsigned int*)(g),
        (__attribute__((address_space(3))) unsigned int*)(l), 16, 0, 0);
}

// ---------------------------------------------------------------------------
// x fp32 -> bf16 (same layout).
// ---------------------------------------------------------------------------
__global__ __launch_bounds__(256) void convert_x_kernel(
    const float* __restrict__ x, unsigned short* __restrict__ xb)
{
    size_t i = ((size_t)blockIdx.x * 256 + threadIdx.x) * 8;
    float4 a = *(const float4*)(x + i);
    float4 b = *(const float4*)(x + i + 4);
    ushort8 o;
    o[0] = f2bf(a.x); o[1] = f2bf(a.y); o[2] = f2bf(a.z); o[3] = f2bf(a.w);
    o[4] = f2bf(b.x); o[5] = f2bf(b.y); o[6] = f2bf(b.z); o[7] = f2bf(b.w);
    *(ushort8*)(xb + i) = o;
}

// ---------------------------------------------------------------------------
// W [k][n] fp32 -> Wt [mat][n][k] bf16 (transpose), 64x64 tiles via LDS.
// ---------------------------------------------------------------------------
__global__ __launch_bounds__(256) void transpose_w_kernel(
    const float* __restrict__ Wq, const float* __restrict__ Wk,
    const float* __restrict__ Wv, const float* __restrict__ Wo,
    unsigned short* __restrict__ Wt)
{
    __shared__ float tile[64][65];
    const int z = blockIdx.z;
    const float* W = (z == 0) ? Wq : (z == 1) ? Wk : (z == 2) ? Wv : Wo;
    unsigned short* outp = Wt + (size_t)z * Kdim * Ddim;
    const int n0 = blockIdx.x * 64;
    const int k0 = blockIdx.y * 64;
    const int t = threadIdx.x;
#pragma unroll
    for (int i = 0; i < 4; ++i) {
        int flat = i * 256 + t;
        int r = flat >> 4;
        int c = (flat & 15) * 4;
        float4 v = *(const float4*)(W + (size_t)(k0 + r) * Ddim + n0 + c);
        tile[r][c] = v.x; tile[r][c + 1] = v.y; tile[r][c + 2] = v.z; tile[r][c + 3] = v.w;
    }
    __syncthreads();
#pragma unroll
    for (int i = 0; i < 16; ++i) {
        int flat = i * 256 + t;
        int n = flat >> 6;
        int k = flat & 63;
        outp[(size_t)(n0 + n) * Kdim + k0 + k] = f2bf(tile[k][n]);
    }
}

// ---------------------------------------------------------------------------
// Pack mask into per-wave lane-mask words:
// word[b][qg][kb16][r], bit(lane) = mask[b][qg*16+(lane&15)][kb16*16+(lane>>4)*4+r]
// ---------------------------------------------------------------------------
__global__ __launch_bounds__(256) void pack_mask_kernel(
    const int* __restrict__ mask, unsigned long long* __restrict__ packed)
{
    const int t    = threadIdx.x;
    const int lane = t & 63;
    const int l15  = lane & 15;
    const int quad = lane >> 4;
    const unsigned int widx = blockIdx.x * 4 + (t >> 6);
    const int r  = widx & 3;
    const int kb = (widx >> 2) & 127;
    const int qg = (widx >> 9) & 127;
    const int b  = widx >> 16;
    int mv = mask[((size_t)(b * Sdim) + qg * 16 + l15) * Sdim + kb * 16 + quad * 4 + r];
    unsigned long long bits = __ballot(mv != 0);
    if (lane == 0) packed[widx] = bits;
}

// ---------------------------------------------------------------------------
// bf16 MFMA GEMM K-loop (m97 structure), 128 x BN tile, BK=64.
// MFMA_NORM: C (lane=n-col, regs=m-rows).  MFMA_SWAP: C^T (lane=m, regs=n).
// ---------------------------------------------------------------------------
#define MFMA_NORM(MT, NT) acc[MT][NT] = __builtin_amdgcn_mfma_f32_16x16x32_bf16(af[MT], bfr[NT], acc[MT][NT], 0, 0, 0)
#define MFMA_SWAP(MT, NT) acc[MT][NT] = __builtin_amdgcn_mfma_f32_16x16x32_bf16(bfr[NT], af[MT], acc[MT][NT], 0, 0, 0)

// NT_TILES in {2,4}; A-tile rows=128, B-tile rows = NT_TILES*32.
#define GEMM_KLOOP(APTR, WPTR, NT_TILES, MFMA_STMT)                              \
    for (int kt = 0; kt < 16; ++kt) {                                            \
        const int k0 = kt * 64;                                                  \
        __syncthreads();                                                         \
        _Pragma("unroll")                                                        \
        for (int i = 0; i < 4; ++i) {                                            \
            int flat = i * 256 + t;                                              \
            int row  = flat >> 3;                                                \
            int cg   = (flat & 7) ^ (row & 7);                                   \
            async_ld16(APTR + (size_t)(m0 + row) * Kdim + k0 + cg * 8,           \
                       As + flat * 8);                                           \
        }                                                                        \
        _Pragma("unroll")                                                        \
        for (int i = 0; i < NT_TILES; ++i) {                                     \
            int flat = i * 256 + t;                                              \
            int row  = flat >> 3;                                                \
            int cg   = (flat & 7) ^ (row & 7);                                   \
            async_ld16(WPTR + (size_t)row * Kdim + k0 + cg * 8,                  \
                       Bs + flat * 8);                                           \
        }                                                                        \
        __syncthreads();                                                         \
        _Pragma("unroll")                                                        \
        for (int ks = 0; ks < 2; ++ks) {                                         \
            short8 af[4], bfr[NT_TILES];                                         \
            _Pragma("unroll")                                                    \
            for (int mt = 0; mt < 4; ++mt) {                                     \
                int row = wm * 64 + mt * 16 + l15;                               \
                int ch  = (ks * 4 + quad) ^ (row & 7);                           \
                af[mt] = *(const short8*)(As + row * 64 + ch * 8);               \
            }                                                                    \
            _Pragma("unroll")                                                    \
            for (int nt = 0; nt < NT_TILES; ++nt) {                              \
                int row = wn * (NT_TILES * 16) + nt * 16 + l15;                  \
                int ch  = (ks * 4 + quad) ^ (row & 7);                           \
                bfr[nt] = *(const short8*)(Bs + row * 64 + ch * 8);              \
            }                                                                    \
            _Pragma("unroll")                                                    \
            for (int mt = 0; mt < 4; ++mt)                                       \
                _Pragma("unroll")                                                \
                for (int nt = 0; nt < NT_TILES; ++nt)                            \
                    MFMA_STMT(mt, nt);                                           \
        }                                                                        \
    }

// ---------------------------------------------------------------------------
// Fused QKV projection: grid (24, 32) = 768 blocks (3/CU). Block-uniform
// branch: q/k blocks use swapped MFMA (C^T -> ushort4 stores along hd);
// v blocks use normal MFMA (regs = 4 contiguous s -> half4 transposed stores).
// ---------------------------------------------------------------------------
__global__ __launch_bounds__(256) void qkv_mfma_kernel(
    const unsigned short* __restrict__ A, const unsigned short* __restrict__ Wt,
    const float* __restrict__ bq, const float* __restrict__ bk, const float* __restrict__ bv,
    unsigned short* __restrict__ qo, unsigned short* __restrict__ ko, _Float16* __restrict__ vto)
{
    __shared__ __align__(16) unsigned short As[128 * 64];
    __shared__ __align__(16) unsigned short Bs[128 * 64];
    const int n0   = blockIdx.x * 128;
    const int m0   = blockIdx.y * 128;
    const int wsel = n0 >> 10;
    const int c0   = n0 & 1023;
    const unsigned short* Wp = Wt + (size_t)wsel * Kdim * Ddim + (size_t)c0 * Kdim;

    const int t    = threadIdx.x;
    const int lane = t & 63;
    const int w    = t >> 6;
    const int quad = lane >> 4;
    const int l15  = lane & 15;
    const int wm   = w & 1;
    const int wn   = w >> 1;
    floatx4 acc[4][4];
#pragma unroll
    for (int mt = 0; mt < 4; ++mt)
#pragma unroll
        for (int nt = 0; nt < 4; ++nt) acc[mt][nt] = (floatx4){0.f, 0.f, 0.f, 0.f};

    if (wsel < 2) {
        GEMM_KLOOP(A, Wp, 4, MFMA_SWAP)
        const float* bias = wsel ? bk : bq;
        unsigned short* outp = wsel ? ko : qo;
        const float qsc = wsel ? 1.0f : 0.18033688011112042f;  // q: 0.125*log2(e)
#pragma unroll
        for (int mt = 0; mt < 4; ++mt) {
            int m    = m0 + wm * 64 + mt * 16 + l15;  // s-row
            int bidx = m >> 11;
            int s    = m & 2047;
#pragma unroll
            for (int nt = 0; nt < 4; ++nt) {
                int c = c0 + wn * 64 + nt * 16 + quad * 4;  // 4 contiguous cols
                float4 bb = *(const float4*)(bias + c);
                int h  = c >> 6;
                int hd = c & 63;
                ushort4v o;
                o[0] = f2bf((acc[mt][nt][0] + bb.x) * qsc);
                o[1] = f2bf((acc[mt][nt][1] + bb.y) * qsc);
                o[2] = f2bf((acc[mt][nt][2] + bb.z) * qsc);
                o[3] = f2bf((acc[mt][nt][3] + bb.w) * qsc);
                *(ushort4v*)(outp + ((size_t)(bidx * Hnum + h) * Sdim + s) * HDdim + hd) = o;
            }
        }
    } else {
        GEMM_KLOOP(A, Wp, 4, MFMA_NORM)
#pragma unroll
        for (int nt = 0; nt < 4; ++nt) {
            int c = c0 + wn * 64 + nt * 16 + l15;
            float bb = bv[c];
            int h  = c >> 6;
            int hd = c & 63;
#pragma unroll
            for (int mt = 0; mt < 4; ++mt) {
                int m    = m0 + wm * 64 + mt * 16 + quad * 4;  // 4 contiguous s
                int bidx = m >> 11;
                int s    = m & 2047;
                half4 o;
#pragma unroll
                for (int r = 0; r < 4; ++r) o[r] = (_Float16)(acc[mt][nt][r] + bb);
                *(half4*)(vto + ((size_t)(bidx * Hnum + h) * HDdim + hd) * Sdim + s) = o;
            }
        }
    }
}

// ---------------------------------------------------------------------------
// Output projection (operand-swapped), 128x64 tiles: grid (16, 32) = 512
// blocks (2/CU). fp32 out + bias, float4 coalesced stores.
// ---------------------------------------------------------------------------
__global__ __launch_bounds__(256) void out_mfma_kernel(
    const unsigned short* __restrict__ A, const unsigned short* __restrict__ Wt,
    const float* __restrict__ bias, float* __restrict__ out)
{
    __shared__ __align__(16) unsigned short As[128 * 64];
    __shared__ __align__(16) unsigned short Bs[64 * 64];
    const int n0 = blockIdx.x * 64;
    const int m0 = blockIdx.y * 128;
    const unsigned short* Wp = Wt + (size_t)3 * Kdim * Ddim + (size_t)n0 * Kdim;

    const int t    = threadIdx.x;
    const int lane = t & 63;
    const int w    = t >> 6;
    const int quad = lane >> 4;
    const int l15  = lane & 15;
    const int wm   = w & 1;
    const int wn   = w >> 1;
    floatx4 acc[4][2];
#pragma unroll
    for (int mt = 0; mt < 4; ++mt)
#pragma unroll
        for (int nt = 0; nt < 2; ++nt) acc[mt][nt] = (floatx4){0.f, 0.f, 0.f, 0.f};

    GEMM_KLOOP(A, Wp, 2, MFMA_SWAP)

#pragma unroll
    for (int mt = 0; mt < 4; ++mt) {
        int m = m0 + wm * 64 + mt * 16 + l15;  // s-row
#pragma unroll
        for (int nt = 0; nt < 2; ++nt) {
            int c = n0 + wn * 32 + nt * 16 + quad * 4;
            float4 bb = *(const float4*)(bias + c);
            float4 o = make_float4(acc[mt][nt][0] + bb.x, acc[mt][nt][1] + bb.y,
                                   acc[mt][nt][2] + bb.z, acc[mt][nt][3] + bb.w);
            *(float4*)(out + (size_t)m * Ddim + c) = o;
        }
    }
}

// ---------------------------------------------------------------------------
// MFMA flash attention v3 (unchanged): DMA-staged K/V (double-buffered LDS),
// transposed scores, P in registers, mask via SGPR v_cndmask, l via ones-MFMA.
// Block = 2 waves x 64 q-rows; grid 1024, bh = bid&31.
// ---------------------------------------------------------------------------
__global__ __launch_bounds__(128, 2) void attn_mfma_kernel(
    const unsigned short* __restrict__ q, const unsigned short* __restrict__ k,
    const _Float16* __restrict__ vt, const unsigned long long* __restrict__ pmask,
    unsigned short* __restrict__ ctx)
{
    __shared__ __align__(16) unsigned short Ks[2][64 * 64];  // [key][hd], swizzled
    __shared__ __align__(16) _Float16       Vs[2][64 * 64];  // [hd][key], swizzled

    const int t    = threadIdx.x;
    const int w    = t >> 6;
    const int lane = t & 63;
    const int quad = lane >> 4;
    const int l15  = lane & 15;
    const int bid  = blockIdx.x;
    const int bh   = bid & 31;
    const int qseg = bid >> 5;
    const int b    = bh >> 4;
    const int h    = bh & 15;
    const int qrow0 = qseg * 64 + w * 32;

    const unsigned short* qp = q  + (size_t)bh * Sdim * HDdim;
    const unsigned short* kp = k  + (size_t)bh * Sdim * HDdim;
    const _Float16*       vp = vt + (size_t)bh * HDdim * Sdim;

    const int qg0 = __builtin_amdgcn_readfirstlane(qrow0 >> 4);
    const unsigned long long* __restrict__ pm =
        pmask + ((size_t)(b * 128 + qg0) * 128) * 4;

    short8 qf[2][2];
#pragma unroll
    for (int g = 0; g < 2; ++g)
#pragma unroll
        for (int ks = 0; ks < 2; ++ks)
            qf[g][ks] = *(const short8*)(qp + (size_t)(qrow0 + g * 16 + l15) * HDdim + ks * 32 + quad * 8);

    floatx4 acc[2][4];
    floatx4 accl[2];
#pragma unroll
    for (int g = 0; g < 2; ++g) {
        accl[g] = (floatx4){0.f, 0.f, 0.f, 0.f};
#pragma unroll
        for (int hs = 0; hs < 4; ++hs) acc[g][hs] = (floatx4){0.f, 0.f, 0.f, 0.f};
    }
    const half4 ones = {(_Float16)1.f, (_Float16)1.f, (_Float16)1.f, (_Float16)1.f};

    auto stage = [&](int buf, int key0) {
#pragma unroll
        for (int i = 0; i < 4; ++i) {
            int flat = i * 128 + t;
            int row  = flat >> 3;
            int cg   = (flat & 7) ^ (row & 7);
            async_ld16(kp + (size_t)(key0 + row) * HDdim + cg * 8, &Ks[buf][flat * 8]);
        }
#pragma unroll
        for (int i = 0; i < 4; ++i) {
            int flat = i * 128 + t;
            int row  = flat >> 3;
            int cg   = (flat & 7) ^ (row & 7);
            async_ld16((const unsigned short*)(vp + (size_t)row * Sdim + key0 + cg * 8),
                       (unsigned short*)&Vs[buf][flat * 8]);
        }
    };

    stage(0, 0);

#pragma unroll 2
    for (int kt = 0; kt < 32; ++kt) {
        const int cur = kt & 1;
        __syncthreads();
        if (kt < 31) stage(cur ^ 1, (kt + 1) * 64);

        short8 kf[2][4];
#pragma unroll
        for (int ks = 0; ks < 2; ++ks)
#pragma unroll
            for (int sub = 0; sub < 4; ++sub) {
                int row = sub * 16 + l15;
                int ch  = (ks * 4 + quad) ^ (row & 7);
                kf[ks][sub] = *(const short8*)&Ks[cur][row * 64 + ch * 8];
            }
        half4 vf[4][4];
#pragma unroll
        for (int hs = 0; hs < 4; ++hs)
#pragma unroll
            for (int c = 0; c < 4; ++c) {
                int row = hs * 16 + l15;
                int cc  = c * 2 + (quad >> 1);
                int ch  = cc ^ (row & 7);
                vf[hs][c] = *(const half4*)&Vs[cur][row * 64 + ch * 8 + (quad & 1) * 4];
            }

        floatx4 sc[2][4];
#pragma unroll
        for (int g = 0; g < 2; ++g)
#pragma unroll
            for (int sub = 0; sub < 4; ++sub) sc[g][sub] = (floatx4){0.f, 0.f, 0.f, 0.f};
#pragma unroll
        for (int ks = 0; ks < 2; ++ks)
#pragma unroll
            for (int sub = 0; sub < 4; ++sub)
#pragma unroll
                for (int g = 0; g < 2; ++g)
                    sc[g][sub] = __builtin_amdgcn_mfma_f32_16x16x32_bf16(
                        kf[ks][sub], qf[g][ks], sc[g][sub], 0, 0, 0);

        half4 pf[2][4];
#pragma unroll
        for (int g = 0; g < 2; ++g) {
            const unsigned long long* __restrict__ pg = pm + g * 512 + kt * 16;
#pragma unroll
            for (int c = 0; c < 4; ++c) {
#pragma unroll
                for (int r = 0; r < 4; ++r) {
                    float p = exp2f(sc[g][c][r]);
                    unsigned long long wmask = pg[c * 4 + r];
                    float pmv;
                    asm("v_cndmask_b32 %0, 0, %1, %2" : "=v"(pmv) : "v"(p), "s"(wmask));
                    pf[g][c][r] = (_Float16)pmv;
                }
            }
        }

#pragma unroll
        for (int c = 0; c < 4; ++c) {
#pragma unroll
            for (int hs = 0; hs < 4; ++hs)
#pragma unroll
                for (int g = 0; g < 2; ++g)
                    acc[g][hs] = __builtin_amdgcn_mfma_f32_16x16x16f16(
                        vf[hs][c], pf[g][c], acc[g][hs], 0, 0, 0);
#pragma unroll
            for (int g = 0; g < 2; ++g)
                accl[g] = __builtin_amdgcn_mfma_f32_16x16x16f16(
                    ones, pf[g][c], accl[g], 0, 0, 0);
        }
    }

#pragma unroll
    for (int g = 0; g < 2; ++g) {
        float inv = 1.0f / fmaxf(accl[g][0], 1e-30f);
        int row = qrow0 + g * 16 + l15;
#pragma unroll
        for (int hs = 0; hs < 4; ++hs) {
            ushort4v o;
#pragma unroll
            for (int r = 0; r < 4; ++r) o[r] = f2bf(acc[g][hs][r] * inv);
            *(ushort4v*)(ctx + (size_t)(b * Sdim + row) * Ddim + h * 64 + hs * 16 + quad * 4) = o;
        }
    }
}

// ---------------------------------------------------------------------------
extern "C" void kernel_launch(void* const* d_in, const int* in_sizes, int n_in,
                              void* d_out, int out_size, void* d_ws, size_t ws_size,
                              hipStream_t stream) {
    const float* x   = (const float*)d_in[0];
    const float* Wq  = (const float*)d_in[1];
    const float* bq  = (const float*)d_in[2];
    const float* Wk  = (const float*)d_in[3];
    const float* bk  = (const float*)d_in[4];
    const float* Wv  = (const float*)d_in[5];
    const float* bv  = (const float*)d_in[6];
    const float* Wo  = (const float*)d_in[7];
    const float* bo  = (const float*)d_in[8];
    // d_in[9] cross_modal_weights: softmax-shift-invariant -> unused
    const int*  mask = (const int*)d_in[10];
    // d_in[11] modality_info: unused by the reference
    float* out = (float*)d_out;

    char* ws = (char*)d_ws;
    unsigned short* xb  = (unsigned short*)(ws);                         // 8 MB
    unsigned short* Wt  = (unsigned short*)(ws + (size_t)8  * 1048576);  // 8 MB
    unsigned short* qb  = (unsigned short*)(ws + (size_t)16 * 1048576);  // 8 MB
    unsigned short* kb  = (unsigned short*)(ws + (size_t)24 * 1048576);  // 8 MB
    _Float16*       vtb = (_Float16*)     (ws + (size_t)32 * 1048576);   // 8 MB f16 [bh][hd][s]
    unsigned long long* pmk = (unsigned long long*)(ws + (size_t)40 * 1048576); // 1 MB
    unsigned short* ctxb = xb;  // alias: xb consumed before attn writes ctx

    convert_x_kernel<<<dim3(2048), 256, 0, stream>>>(x, xb);
    transpose_w_kernel<<<dim3(16, 16, 4), 256, 0, stream>>>(Wq, Wk, Wv, Wo, Wt);
    pack_mask_kernel<<<dim3(32768), 256, 0, stream>>>(mask, pmk);
    qkv_mfma_kernel<<<dim3(24, 32), 256, 0, stream>>>(xb, Wt, bq, bk, bv, qb, kb, vtb);
    attn_mfma_kernel<<<dim3(1024), 128, 0, stream>>>(qb, kb, vtb, pmk, ctxb);
    out_mfma_kernel<<<dim3(16, 32), 256, 0, stream>>>(ctxb, Wt, bo, out);
}

// Round 9
// 254.617 us; speedup vs baseline: 1.1371x; 1.0819x over previous
//
#include <hip/hip_runtime.h>
#include <math.h>

#define Bdim 2
#define Sdim 2048
#define Ddim 1024
#define Hnum 16
#define HDdim 64
#define Kdim 1024

using short8   = __attribute__((ext_vector_type(8))) short;
using ushort8  = __attribute__((ext_vector_type(8))) unsigned short;
using ushort4v = __attribute__((ext_vector_type(4))) unsigned short;
using floatx4  = __attribute__((ext_vector_type(4))) float;
using half4    = __attribute__((ext_vector_type(4))) _Float16;
using half2v   = __attribute__((ext_vector_type(2))) _Float16;

__device__ __forceinline__ unsigned short f2bf(float f) {
    __bf16 b = (__bf16)f;
    return __builtin_bit_cast(unsigned short, b);
}

// async global->LDS, 16B per lane. LDS dest is wave-uniform base + lane*16.
__device__ __forceinline__ void async_ld16(const unsigned short* g, unsigned short* l) {
    __builtin_amdgcn_global_load_lds(
        (const __attribute__((address_space(1))) unsigned int*)(g),
        (__attribute__((address_space(3))) unsigned int*)(l), 16, 0, 0);
}

// ---------------------------------------------------------------------------
// Fused prep: [0,2048) x fp32->bf16; [2048,3072) W transpose->bf16 [n][k];
// [3072,11264) mask int32 -> per-wave lane-mask words (int4 + 4 ballots).
// ---------------------------------------------------------------------------
__global__ __launch_bounds__(256) void prep_kernel(
    const float* __restrict__ x,
    const float* __restrict__ Wq, const float* __restrict__ Wk,
    const float* __restrict__ Wv, const float* __restrict__ Wo,
    const int* __restrict__ mask,
    unsigned short* __restrict__ xb, unsigned short* __restrict__ Wt,
    unsigned long long* __restrict__ packed)
{
    __shared__ float tile[64][65];
    const int bid = blockIdx.x;
    const int t   = threadIdx.x;

    if (bid < 2048) {
        // ---- x -> bf16 ----
        size_t i = ((size_t)bid * 256 + t) * 8;
        float4 a = *(const float4*)(x + i);
        float4 b = *(const float4*)(x + i + 4);
        ushort8 o;
        o[0] = f2bf(a.x); o[1] = f2bf(a.y); o[2] = f2bf(a.z); o[3] = f2bf(a.w);
        o[4] = f2bf(b.x); o[5] = f2bf(b.y); o[6] = f2bf(b.z); o[7] = f2bf(b.w);
        *(ushort8*)(xb + i) = o;
    } else if (bid < 3072) {
        // ---- W [k][n] -> Wt [z][n][k] bf16, 64x64 tiles ----
        const int idx = bid - 2048;
        const int n0 = (idx & 15) * 64;
        const int k0 = ((idx >> 4) & 15) * 64;
        const int z  = idx >> 8;
        const float* W = (z == 0) ? Wq : (z == 1) ? Wk : (z == 2) ? Wv : Wo;
        unsigned short* outp = Wt + (size_t)z * Kdim * Ddim;
#pragma unroll
        for (int i = 0; i < 4; ++i) {
            int flat = i * 256 + t;
            int r = flat >> 4;
            int c = (flat & 15) * 4;
            float4 v = *(const float4*)(W + (size_t)(k0 + r) * Ddim + n0 + c);
            tile[r][c] = v.x; tile[r][c+1] = v.y; tile[r][c+2] = v.z; tile[r][c+3] = v.w;
        }
        __syncthreads();
#pragma unroll
        for (int i = 0; i < 16; ++i) {
            int flat = i * 256 + t;
            int n = flat >> 6;
            int k = flat & 63;
            outp[(size_t)(n0 + n) * Kdim + k0 + k] = f2bf(tile[k][n]);
        }
    } else {
        // ---- mask pack: wave group gid=(b,qg,kb); lane (l15,quad) reads int4,
        //      4 ballots give words [gid*4 + r],
        //      bit(lane) = mask[b][qg*16+l15][kb*16+quad*4+r] ----
        const int lane = t & 63;
        const int l15  = lane & 15;
        const int quad = lane >> 4;
        const unsigned int gid = (bid - 3072) * 4 + (t >> 6);
        const int b  = gid >> 14;
        const int qg = (gid >> 7) & 127;
        const int kb = gid & 127;
        int4 mv = *(const int4*)(mask + ((size_t)(b * Sdim) + qg * 16 + l15) * Sdim + kb * 16 + quad * 4);
        unsigned long long w0 = __ballot(mv.x != 0);
        unsigned long long w1 = __ballot(mv.y != 0);
        unsigned long long w2 = __ballot(mv.z != 0);
        unsigned long long w3 = __ballot(mv.w != 0);
        if (lane == 0) {
            unsigned long long* dst = packed + (size_t)gid * 4;
            dst[0] = w0; dst[1] = w1; dst[2] = w2; dst[3] = w3;
        }
    }
}

// ---------------------------------------------------------------------------
// bf16 MFMA GEMM K-loop (m97 structure), 128 x BN tile, BK=64.
// MFMA_NORM: C (lane=n-col, regs=m-rows).  MFMA_SWAP: C^T (lane=m, regs=n).
// ---------------------------------------------------------------------------
#define MFMA_NORM(MT, NT) acc[MT][NT] = __builtin_amdgcn_mfma_f32_16x16x32_bf16(af[MT], bfr[NT], acc[MT][NT], 0, 0, 0)
#define MFMA_SWAP(MT, NT) acc[MT][NT] = __builtin_amdgcn_mfma_f32_16x16x32_bf16(bfr[NT], af[MT], acc[MT][NT], 0, 0, 0)

#define GEMM_KLOOP(APTR, WPTR, NT_TILES, MFMA_STMT)                              \
    for (int kt = 0; kt < 16; ++kt) {                                            \
        const int k0 = kt * 64;                                                  \
        __syncthreads();                                                         \
        _Pragma("unroll")                                                        \
        for (int i = 0; i < 4; ++i) {                                            \
            int flat = i * 256 + t;                                              \
            int row  = flat >> 3;                                                \
            int cg   = (flat & 7) ^ (row & 7);                                   \
            async_ld16(APTR + (size_t)(m0 + row) * Kdim + k0 + cg * 8,           \
                       As + flat * 8);                                           \
        }                                                                        \
        _Pragma("unroll")                                                        \
        for (int i = 0; i < NT_TILES; ++i) {                                     \
            int flat = i * 256 + t;                                              \
            int row  = flat >> 3;                                                \
            int cg   = (flat & 7) ^ (row & 7);                                   \
            async_ld16(WPTR + (size_t)row * Kdim + k0 + cg * 8,                  \
                       Bs + flat * 8);                                           \
        }                                                                        \
        __syncthreads();                                                         \
        _Pragma("unroll")                                                        \
        for (int ks = 0; ks < 2; ++ks) {                                         \
            short8 af[4], bfr[NT_TILES];                                         \
            _Pragma("unroll")                                                    \
            for (int mt = 0; mt < 4; ++mt) {                                     \
                int row = wm * 64 + mt * 16 + l15;                               \
                int ch  = (ks * 4 + quad) ^ (row & 7);                           \
                af[mt] = *(const short8*)(As + row * 64 + ch * 8);               \
            }                                                                    \
            _Pragma("unroll")                                                    \
            for (int nt = 0; nt < NT_TILES; ++nt) {                              \
                int row = wn * (NT_TILES * 16) + nt * 16 + l15;                  \
                int ch  = (ks * 4 + quad) ^ (row & 7);                           \
                bfr[nt] = *(const short8*)(Bs + row * 64 + ch * 8);              \
            }                                                                    \
            _Pragma("unroll")                                                    \
            for (int mt = 0; mt < 4; ++mt)                                       \
                _Pragma("unroll")                                                \
                for (int nt = 0; nt < NT_TILES; ++nt)                            \
                    MFMA_STMT(mt, nt);                                           \
        }                                                                        \
    }

// ---------------------------------------------------------------------------
// Fused QKV projection: grid (24, 32) = 768 blocks (3/CU). q/k blocks use
// swapped MFMA (C^T -> ushort4 stores); v blocks normal (half4 transposed).
// ---------------------------------------------------------------------------
__global__ __launch_bounds__(256) void qkv_mfma_kernel(
    const unsigned short* __restrict__ A, const unsigned short* __restrict__ Wt,
    const float* __restrict__ bq, const float* __restrict__ bk, const float* __restrict__ bv,
    unsigned short* __restrict__ qo, unsigned short* __restrict__ ko, _Float16* __restrict__ vto)
{
    __shared__ __align__(16) unsigned short As[128 * 64];
    __shared__ __align__(16) unsigned short Bs[128 * 64];
    const int n0   = blockIdx.x * 128;
    const int m0   = blockIdx.y * 128;
    const int wsel = n0 >> 10;
    const int c0   = n0 & 1023;
    const unsigned short* Wp = Wt + (size_t)wsel * Kdim * Ddim + (size_t)c0 * Kdim;

    const int t    = threadIdx.x;
    const int lane = t & 63;
    const int w    = t >> 6;
    const int quad = lane >> 4;
    const int l15  = lane & 15;
    const int wm   = w & 1;
    const int wn   = w >> 1;
    floatx4 acc[4][4];
#pragma unroll
    for (int mt = 0; mt < 4; ++mt)
#pragma unroll
        for (int nt = 0; nt < 4; ++nt) acc[mt][nt] = (floatx4){0.f, 0.f, 0.f, 0.f};

    if (wsel < 2) {
        GEMM_KLOOP(A, Wp, 4, MFMA_SWAP)
        const float* bias = wsel ? bk : bq;
        unsigned short* outp = wsel ? ko : qo;
        const float qsc = wsel ? 1.0f : 0.18033688011112042f;  // q: 0.125*log2(e)
#pragma unroll
        for (int mt = 0; mt < 4; ++mt) {
            int m    = m0 + wm * 64 + mt * 16 + l15;  // s-row
            int bidx = m >> 11;
            int s    = m & 2047;
#pragma unroll
            for (int nt = 0; nt < 4; ++nt) {
                int c = c0 + wn * 64 + nt * 16 + quad * 4;  // 4 contiguous cols
                float4 bb = *(const float4*)(bias + c);
                int h  = c >> 6;
                int hd = c & 63;
                ushort4v o;
                o[0] = f2bf((acc[mt][nt][0] + bb.x) * qsc);
                o[1] = f2bf((acc[mt][nt][1] + bb.y) * qsc);
                o[2] = f2bf((acc[mt][nt][2] + bb.z) * qsc);
                o[3] = f2bf((acc[mt][nt][3] + bb.w) * qsc);
                *(ushort4v*)(outp + ((size_t)(bidx * Hnum + h) * Sdim + s) * HDdim + hd) = o;
            }
        }
    } else {
        GEMM_KLOOP(A, Wp, 4, MFMA_NORM)
#pragma unroll
        for (int nt = 0; nt < 4; ++nt) {
            int c = c0 + wn * 64 + nt * 16 + l15;
            float bb = bv[c];
            int h  = c >> 6;
            int hd = c & 63;
#pragma unroll
            for (int mt = 0; mt < 4; ++mt) {
                int m    = m0 + wm * 64 + mt * 16 + quad * 4;  // 4 contiguous s
                int bidx = m >> 11;
                int s    = m & 2047;
                half4 o;
#pragma unroll
                for (int r = 0; r < 4; ++r) o[r] = (_Float16)(acc[mt][nt][r] + bb);
                *(half4*)(vto + ((size_t)(bidx * Hnum + h) * HDdim + hd) * Sdim + s) = o;
            }
        }
    }
}

// ---------------------------------------------------------------------------
// Output projection (operand-swapped), 128x64 tiles: grid (16, 32) = 512
// blocks (2/CU). fp32 out + bias, float4 coalesced stores.
// ---------------------------------------------------------------------------
__global__ __launch_bounds__(256) void out_mfma_kernel(
    const unsigned short* __restrict__ A, const unsigned short* __restrict__ Wt,
    const float* __restrict__ bias, float* __restrict__ out)
{
    __shared__ __align__(16) unsigned short As[128 * 64];
    __shared__ __align__(16) unsigned short Bs[64 * 64];
    const int n0 = blockIdx.x * 64;
    const int m0 = blockIdx.y * 128;
    const unsigned short* Wp = Wt + (size_t)3 * Kdim * Ddim + (size_t)n0 * Kdim;

    const int t    = threadIdx.x;
    const int lane = t & 63;
    const int w    = t >> 6;
    const int quad = lane >> 4;
    const int l15  = lane & 15;
    const int wm   = w & 1;
    const int wn   = w >> 1;
    floatx4 acc[4][2];
#pragma unroll
    for (int mt = 0; mt < 4; ++mt)
#pragma unroll
        for (int nt = 0; nt < 2; ++nt) acc[mt][nt] = (floatx4){0.f, 0.f, 0.f, 0.f};

    GEMM_KLOOP(A, Wp, 2, MFMA_SWAP)

#pragma unroll
    for (int mt = 0; mt < 4; ++mt) {
        int m = m0 + wm * 64 + mt * 16 + l15;  // s-row
#pragma unroll
        for (int nt = 0; nt < 2; ++nt) {
            int c = n0 + wn * 32 + nt * 16 + quad * 4;
            float4 bb = *(const float4*)(bias + c);
            float4 o = make_float4(acc[mt][nt][0] + bb.x, acc[mt][nt][1] + bb.y,
                                   acc[mt][nt][2] + bb.z, acc[mt][nt][3] + bb.w);
            *(float4*)(out + (size_t)m * Ddim + c) = o;
        }
    }
}

// ---------------------------------------------------------------------------
// MFMA flash attention v4: 256-thr blocks (4 waves SHARE one K/V staging ->
// half the DMA/L2 traffic of v3), double-buffered LDS, transposed scores,
// P in registers (cvt_pkrtz pack), mask via SGPR v_cndmask, l via ones-MFMA.
// Each wave owns 32 q-rows; block covers 128. Grid 512, bh = bid&31.
// ---------------------------------------------------------------------------
__global__ __launch_bounds__(256, 2) void attn_mfma_kernel(
    const unsigned short* __restrict__ q, const unsigned short* __restrict__ k,
    const _Float16* __restrict__ vt, const unsigned long long* __restrict__ pmask,
    unsigned short* __restrict__ ctx)
{
    __shared__ __align__(16) unsigned short Ks[2][64 * 64];  // [key][hd], swizzled
    __shared__ __align__(16) _Float16       Vs[2][64 * 64];  // [hd][key], swizzled

    const int t    = threadIdx.x;
    const int w    = t >> 6;
    const int lane = t & 63;
    const int quad = lane >> 4;
    const int l15  = lane & 15;
    const int bid  = blockIdx.x;
    const int bh   = bid & 31;
    const int qseg = bid >> 5;
    const int b    = bh >> 4;
    const int h    = bh & 15;
    const int qrow0 = qseg * 128 + w * 32;

    const unsigned short* qp = q  + (size_t)bh * Sdim * HDdim;
    const unsigned short* kp = k  + (size_t)bh * Sdim * HDdim;
    const _Float16*       vp = vt + (size_t)bh * HDdim * Sdim;

    const int qg0 = __builtin_amdgcn_readfirstlane(qrow0 >> 4);
    const unsigned long long* __restrict__ pm =
        pmask + ((size_t)(b * 128 + qg0) * 128) * 4;

    short8 qf[2][2];
#pragma unroll
    for (int g = 0; g < 2; ++g)
#pragma unroll
        for (int ks = 0; ks < 2; ++ks)
            qf[g][ks] = *(const short8*)(qp + (size_t)(qrow0 + g * 16 + l15) * HDdim + ks * 32 + quad * 8);

    floatx4 acc[2][4];
    floatx4 accl[2];
#pragma unroll
    for (int g = 0; g < 2; ++g) {
        accl[g] = (floatx4){0.f, 0.f, 0.f, 0.f};
#pragma unroll
        for (int hs = 0; hs < 4; ++hs) acc[g][hs] = (floatx4){0.f, 0.f, 0.f, 0.f};
    }
    const half4 ones = {(_Float16)1.f, (_Float16)1.f, (_Float16)1.f, (_Float16)1.f};

    // stage key-tile into buf: 256 threads x (2 K + 2 V) DMA insts.
    auto stage = [&](int buf, int key0) {
#pragma unroll
        for (int i = 0; i < 2; ++i) {
            int flat = i * 256 + t;
            int row  = flat >> 3;
            int cg   = (flat & 7) ^ (row & 7);
            async_ld16(kp + (size_t)(key0 + row) * HDdim + cg * 8, &Ks[buf][flat * 8]);
        }
#pragma unroll
        for (int i = 0; i < 2; ++i) {
            int flat = i * 256 + t;
            int row  = flat >> 3;
            int cg   = (flat & 7) ^ (row & 7);
            async_ld16((const unsigned short*)(vp + (size_t)row * Sdim + key0 + cg * 8),
                       (unsigned short*)&Vs[buf][flat * 8]);
        }
    };

    stage(0, 0);

#pragma unroll 2
    for (int kt = 0; kt < 32; ++kt) {
        const int cur = kt & 1;
        __syncthreads();
        if (kt < 31) stage(cur ^ 1, (kt + 1) * 64);

        short8 kf[2][4];
#pragma unroll
        for (int ks = 0; ks < 2; ++ks)
#pragma unroll
            for (int sub = 0; sub < 4; ++sub) {
                int row = sub * 16 + l15;
                int ch  = (ks * 4 + quad) ^ (row & 7);
                kf[ks][sub] = *(const short8*)&Ks[cur][row * 64 + ch * 8];
            }
        half4 vf[4][4];
#pragma unroll
        for (int hs = 0; hs < 4; ++hs)
#pragma unroll
            for (int c = 0; c < 4; ++c) {
                int row = hs * 16 + l15;
                int cc  = c * 2 + (quad >> 1);
                int ch  = cc ^ (row & 7);
                vf[hs][c] = *(const half4*)&Vs[cur][row * 64 + ch * 8 + (quad & 1) * 4];
            }

        floatx4 sc[2][4];
#pragma unroll
        for (int g = 0; g < 2; ++g)
#pragma unroll
            for (int sub = 0; sub < 4; ++sub) sc[g][sub] = (floatx4){0.f, 0.f, 0.f, 0.f};
#pragma unroll
        for (int ks = 0; ks < 2; ++ks)
#pragma unroll
            for (int sub = 0; sub < 4; ++sub)
#pragma unroll
                for (int g = 0; g < 2; ++g)
                    sc[g][sub] = __builtin_amdgcn_mfma_f32_16x16x32_bf16(
                        kf[ks][sub], qf[g][ks], sc[g][sub], 0, 0, 0);

        half4 pf[2][4];
#pragma unroll
        for (int g = 0; g < 2; ++g) {
            const unsigned long long* __restrict__ pg = pm + g * 512 + kt * 16;
#pragma unroll
            for (int c = 0; c < 4; ++c) {
                float pv[4];
#pragma unroll
                for (int r = 0; r < 4; ++r) {
                    float p = exp2f(sc[g][c][r]);
                    unsigned long long wmask = pg[c * 4 + r];
                    asm("v_cndmask_b32 %0, 0, %1, %2" : "=v"(pv[r]) : "v"(p), "s"(wmask));
                }
                half2v lo = __builtin_bit_cast(half2v, __builtin_amdgcn_cvt_pkrtz(pv[0], pv[1]));
                half2v hi = __builtin_bit_cast(half2v, __builtin_amdgcn_cvt_pkrtz(pv[2], pv[3]));
                pf[g][c][0] = lo[0]; pf[g][c][1] = lo[1];
                pf[g][c][2] = hi[0]; pf[g][c][3] = hi[1];
            }
        }

#pragma unroll
        for (int c = 0; c < 4; ++c) {
#pragma unroll
            for (int hs = 0; hs < 4; ++hs)
#pragma unroll
                for (int g = 0; g < 2; ++g)
                    acc[g][hs] = __builtin_amdgcn_mfma_f32_16x16x16f16(
                        vf[hs][c], pf[g][c], acc[g][hs], 0, 0, 0);
#pragma unroll
            for (int g = 0; g < 2; ++g)
                accl[g] = __builtin_amdgcn_mfma_f32_16x16x16f16(
                    ones, pf[g][c], accl[g], 0, 0, 0);
        }
    }

#pragma unroll
    for (int g = 0; g < 2; ++g) {
        float inv = 1.0f / fmaxf(accl[g][0], 1e-30f);
        int row = qrow0 + g * 16 + l15;
#pragma unroll
        for (int hs = 0; hs < 4; ++hs) {
            ushort4v o;
#pragma unroll
            for (int r = 0; r < 4; ++r) o[r] = f2bf(acc[g][hs][r] * inv);
            *(ushort4v*)(ctx + (size_t)(b * Sdim + row) * Ddim + h * 64 + hs * 16 + quad * 4) = o;
        }
    }
}

// ---------------------------------------------------------------------------
extern "C" void kernel_launch(void* const* d_in, const int* in_sizes, int n_in,
                              void* d_out, int out_size, void* d_ws, size_t ws_size,
                              hipStream_t stream) {
    const float* x   = (const float*)d_in[0];
    const float* Wq  = (const float*)d_in[1];
    const float* bq  = (const float*)d_in[2];
    const float* Wk  = (const float*)d_in[3];
    const float* bk  = (const float*)d_in[4];
    const float* Wv  = (const float*)d_in[5];
    const float* bv  = (const float*)d_in[6];
    const float* Wo  = (const float*)d_in[7];
    const float* bo  = (const float*)d_in[8];
    // d_in[9] cross_modal_weights: softmax-shift-invariant -> unused
    const int*  mask = (const int*)d_in[10];
    // d_in[11] modality_info: unused by the reference
    float* out = (float*)d_out;

    char* ws = (char*)d_ws;
    unsigned short* xb  = (unsigned short*)(ws);                         // 8 MB
    unsigned short* Wt  = (unsigned short*)(ws + (size_t)8  * 1048576);  // 8 MB
    unsigned short* qb  = (unsigned short*)(ws + (size_t)16 * 1048576);  // 8 MB
    unsigned short* kb  = (unsigned short*)(ws + (size_t)24 * 1048576);  // 8 MB
    _Float16*       vtb = (_Float16*)     (ws + (size_t)32 * 1048576);   // 8 MB f16 [bh][hd][s]
    unsigned long long* pmk = (unsigned long long*)(ws + (size_t)40 * 1048576); // 1 MB
    unsigned short* ctxb = xb;  // alias: xb consumed before attn writes ctx

    prep_kernel<<<dim3(11264), 256, 0, stream>>>(x, Wq, Wk, Wv, Wo, mask, xb, Wt, pmk);
    qkv_mfma_kernel<<<dim3(24, 32), 256, 0, stream>>>(xb, Wt, bq, bk, bv, qb, kb, vtb);
    attn_mfma_kernel<<<dim3(512), 256, 0, stream>>>(qb, kb, vtb, pmk, ctxb);
    out_mfma_kernel<<<dim3(16, 32), 256, 0, stream>>>(ctxb, Wt, bo, out);
}